// Round 19
// baseline (91.605 us; speedup 1.0000x reference)
//
#include <hip/hip_runtime.h>
#include <hip/hip_bf16.h>

#define BHN 64
#define LSEQ 1024
#define DIM 128
#define BM 128
#define BN 64
#define NQB (LSEQ / BM)   // 8 q-blocks per bh
#define NROW (BHN * LSEQ) // 65536 rows

typedef _Float16 f16x4 __attribute__((ext_vector_type(4)));
typedef _Float16 f16x8 __attribute__((ext_vector_type(8)));
typedef float f32x4 __attribute__((ext_vector_type(4)));

// ---------------------------------------------------------------------------
// Pass 1: R18 (= R12 plateau, 91.5 us) with ONE change: unnormalized O is
// written to the WORKSPACE as fp16 (16 MB) instead of fp32 Out (32 MB).
// |O| < 6e3 << fp16 max; 5e-4 rel error -> ~2e-3 absolute on the normalized
// output (threshold 0.104). Epilogue reads fp16 partials (f16x8 vectorized)
// and writes fp32 Out once. Saves 32 MB of O traffic (~5 us).
// Everything else identical: BM=128, 512 thr, dbuf LDS 68608 B (2 blocks/CU,
// 16 waves/CU), fp16 swapped-QK^T flash tile, lane-local softmax, re-indexed
// zero-shuffle PV, 1 barrier/tile, stage-then-issue pipeline.
// ---------------------------------------------------------------------------
__global__ __launch_bounds__(512, 4) void attn_pass1(
    const float* __restrict__ Q, const float* __restrict__ K,
    const float* __restrict__ V, _Float16* __restrict__ Oh,
    float* __restrict__ mrow, float* __restrict__ rrow, float* __restrict__ gmax)
{
    __shared__ _Float16 Kf[2][BN][132];   // 33792 B, QK reads conflict-free
    __shared__ _Float16 Vt[2][DIM][68];   // 34816 B; V transposed

    const int tid  = threadIdx.x;
    const int wave = tid >> 6;
    const int lane = tid & 63;
    const int g    = lane >> 4;   // 0..3 lane group
    const int ln   = lane & 15;
    const int L    = blockIdx.x;
    const int i6   = (L >> 6) & 7;
    const int qb   = (L < 256) ? (NQB - 1 - i6) : (i6 & 3);  // pair-sum = 7
    const int bh   = L & 63;                                  // same bh -> same XCD
    const int qrow0 = qb * BM + wave * 16;

    const float* qp = Q + (size_t)bh * LSEQ * DIM;
    const float* kp = K + (size_t)bh * LSEQ * DIM;
    const float* vp = V + (size_t)bh * LSEQ * DIM;

    // V staging role: 4x4 block per thread (rows 4*vrp.., cols vc..vc+3)
    const int vrp = tid >> 5;        // 0..15
    const int vc  = (tid & 31) * 4;  // 0..124

    // ---- pipeline registers (one tile in flight) ----
    float4 kreg[4];
    float4 vreg[4];   // vreg[i] = V[kv0 + 4*vrp + i][vc..vc+3]

    auto issue = [&](int kv0) {
        #pragma unroll
        for (int i = 0; i < 4; ++i) {
            const int f4  = i * 512 + tid;
            const int row = f4 >> 5;
            const int cc  = (f4 & 31) * 4;
            kreg[i] = *(const float4*)(kp + (size_t)(kv0 + row) * DIM + cc);
        }
        #pragma unroll
        for (int i = 0; i < 4; ++i)   // coalesced: half-wave = one 512B row seg
            vreg[i] = *(const float4*)(vp + (size_t)(kv0 + 4 * vrp + i) * DIM + vc);
    };

    auto convert_stage = [&](int b) {   // fp32 regs -> fp16 -> LDS buf b
        #pragma unroll
        for (int i = 0; i < 4; ++i) {
            const int f4  = i * 512 + tid;
            const int row = f4 >> 5;
            const int cc  = (f4 & 31) * 4;
            f16x4 h4;
            h4[0] = (_Float16)kreg[i].x; h4[1] = (_Float16)kreg[i].y;
            h4[2] = (_Float16)kreg[i].z; h4[3] = (_Float16)kreg[i].w;
            *(f16x4*)&Kf[b][row][cc] = h4;
        }
        // 4x4 in-register transpose -> column writes (ds_write_b64)
        const float* v0 = (const float*)&vreg[0];
        const float* v1 = (const float*)&vreg[1];
        const float* v2 = (const float*)&vreg[2];
        const float* v3 = (const float*)&vreg[3];
        #pragma unroll
        for (int jj = 0; jj < 4; ++jj) {
            f16x4 t;
            t[0] = (_Float16)v0[jj]; t[1] = (_Float16)v1[jj];
            t[2] = (_Float16)v2[jj]; t[3] = (_Float16)v3[jj];
            *(f16x4*)&Vt[b][vc + jj][4 * vrp] = t;
        }
    };

    // --- Q fragments (B-operand of swapped QK): lane holds
    //     Q[qrow0+ln][kc*32 + g*8 + e] in fp16 ---
    f16x8 qf[4];
    {
        const float* qrow = qp + (size_t)(qrow0 + ln) * DIM;
        #pragma unroll
        for (int kc = 0; kc < 4; ++kc) {
            const int d0 = kc * 32 + g * 8;
            float4 f0 = *(const float4*)(qrow + d0);
            float4 f1 = *(const float4*)(qrow + d0 + 4);
            f16x8 h;
            h[0] = (_Float16)f0.x; h[1] = (_Float16)f0.y;
            h[2] = (_Float16)f0.z; h[3] = (_Float16)f0.w;
            h[4] = (_Float16)f1.x; h[5] = (_Float16)f1.y;
            h[6] = (_Float16)f1.z; h[7] = (_Float16)f1.w;
            qf[kc] = h;
        }
    }

    float m_st = -1e30f, r_st = 0.f;   // per-lane scalars for q = qrow0+ln
    f32x4 o_acc[8];                    // row q_local=4g+r, col d=16ds+ln
    #pragma unroll
    for (int d = 0; d < 8; ++d) { f32x4 z = {0.f,0.f,0.f,0.f}; o_acc[d] = z; }

    const int nt = 2 * qb + 2;         // nt >= 2 always

    // --- prologue: tile 0 staged, tile 1 in flight ---
    issue(0);
    convert_stage(0);
    issue(BN);
    __syncthreads();

    int cur = 0;
    for (int t = 0; t < nt; ++t) {
        const int kv0 = t * BN;

        // stage t+1 into buf^1 FIRST (reads kreg/vreg of tile t+1), THEN
        // issue t+2 (overwrites kreg/vreg; loads fly through compute+barrier)
        if (t + 1 < nt) {
            convert_stage(cur ^ 1);
            if (t + 2 < nt) issue((t + 2) * BN);
        }

        if (qrow0 + 15 >= kv0) {   // wave-uniform: skip fully-masked tiles
            // --- S^T = K Q^T (single fp16 MFMA per 32-k chunk) ---
            f32x4 sacc[4];
            #pragma unroll
            for (int ns = 0; ns < 4; ++ns) { f32x4 z = {0.f,0.f,0.f,0.f}; sacc[ns] = z; }
            __builtin_amdgcn_s_setprio(1);
            #pragma unroll
            for (int ns = 0; ns < 4; ++ns) {
                const int n = ns * 16 + ln;   // A-fragment row
                #pragma unroll
                for (int kc = 0; kc < 4; ++kc) {
                    f16x8 kh_ = *(const f16x8*)&Kf[cur][n][kc * 32 + g * 8];
                    sacc[ns] = __builtin_amdgcn_mfma_f32_16x16x32_f16(kh_, qf[kc], sacc[ns], 0, 0, 0);
                }
            }
            __builtin_amdgcn_s_setprio(0);

            // --- causal mask where the tile crosses the diagonal ---
            if (kv0 + BN - 1 > qrow0) {
                const int qm = qrow0 + ln - kv0 - 4 * g;  // mask if 16ns+j > qm
                #pragma unroll
                for (int ns = 0; ns < 4; ++ns)
                    #pragma unroll
                    for (int j = 0; j < 4; ++j)
                        if (16 * ns + j > qm) sacc[ns][j] = -1e30f;
            }

            // --- online softmax: 16 lane-local values + 2 shfl_xor reduces ---
            float tm = -1e30f;
            #pragma unroll
            for (int ns = 0; ns < 4; ++ns)
                #pragma unroll
                for (int j = 0; j < 4; ++j) tm = fmaxf(tm, sacc[ns][j]);
            tm = fmaxf(tm, __shfl_xor(tm, 16));
            tm = fmaxf(tm, __shfl_xor(tm, 32));
            const float mn = fmaxf(m_st, tm);
            const float sc = __expf(m_st - mn);
            float pr[4][4];
            float ts = 0.f;
            #pragma unroll
            for (int ns = 0; ns < 4; ++ns)
                #pragma unroll
                for (int j = 0; j < 4; ++j) {
                    const float pv = __expf(sacc[ns][j] - mn);
                    pr[ns][j] = pv;
                    ts += pv;
                }
            ts += __shfl_xor(ts, 16);
            ts += __shfl_xor(ts, 32);
            r_st = r_st * sc + ts;
            m_st = mn;

            // rescale factors for accumulator rows (q_local=4g+r -> lane 4g+r)
            float scr[4];
            #pragma unroll
            for (int r = 0; r < 4; ++r) scr[r] = __shfl(sc, 4 * g + r);
            #pragma unroll
            for (int d = 0; d < 8; ++d) {
                o_acc[d][0] *= scr[0]; o_acc[d][1] *= scr[1];
                o_acc[d][2] *= scr[2]; o_acc[d][3] *= scr[3];
            }

            // --- PV, re-indexed contraction: A-frag is the lane's own P ---
            f16x8 pa0, pa1;
            #pragma unroll
            for (int j = 0; j < 4; ++j) {
                pa0[j]     = (_Float16)pr[0][j];
                pa0[4 + j] = (_Float16)pr[1][j];
                pa1[j]     = (_Float16)pr[2][j];
                pa1[4 + j] = (_Float16)pr[3][j];
            }
            __builtin_amdgcn_s_setprio(1);
            #pragma unroll
            for (int ds = 0; ds < 8; ++ds) {
                const int dc = ds * 16 + ln;
                f16x4 v0 = *(const f16x4*)&Vt[cur][dc][4 * g];
                f16x4 v1 = *(const f16x4*)&Vt[cur][dc][16 + 4 * g];
                f16x8 bv0;
                #pragma unroll
                for (int j = 0; j < 4; ++j) { bv0[j] = v0[j]; bv0[4 + j] = v1[j]; }
                o_acc[ds] = __builtin_amdgcn_mfma_f32_16x16x32_f16(pa0, bv0, o_acc[ds], 0, 0, 0);
                f16x4 v2 = *(const f16x4*)&Vt[cur][dc][32 + 4 * g];
                f16x4 v3 = *(const f16x4*)&Vt[cur][dc][48 + 4 * g];
                f16x8 bv1;
                #pragma unroll
                for (int j = 0; j < 4; ++j) { bv1[j] = v2[j]; bv1[4 + j] = v3[j]; }
                o_acc[ds] = __builtin_amdgcn_mfma_f32_16x16x32_f16(pa1, bv1, o_acc[ds], 0, 0, 0);
            }
            __builtin_amdgcn_s_setprio(0);
        }

        __syncthreads();   // publish stage(t+1); protect buf^1 for next overwrite
        cur ^= 1;
    }

    // --- write unnormalized O as fp16 to workspace (q = qrow0+4g+r, d = 16ds+ln) ---
    #pragma unroll
    for (int ds = 0; ds < 8; ++ds) {
        const int dc = ds * 16 + ln;
        #pragma unroll
        for (int r = 0; r < 4; ++r) {
            const int qr = qrow0 + g * 4 + r;
            Oh[((size_t)bh * LSEQ + qr) * DIM + dc] = (_Float16)o_acc[ds][r];
        }
    }
    if (lane < 16) {   // per-lane stats live at q = qrow0 + lane (g = 0)
        mrow[bh * LSEQ + qrow0 + lane] = m_st;
        rrow[bh * LSEQ + qrow0 + lane] = r_st;
    }
    float bm = m_st;
    #pragma unroll
    for (int off = 32; off >= 1; off >>= 1) bm = fmaxf(bm, __shfl_xor(bm, off));
    if (lane == 0) atomicMax((int*)gmax, __float_as_int(bm));
    // int-compare max valid: gmax init +0.0f; negatives always lose (the
    // reference's global max includes the mask's zeros).
}

// ---------------------------------------------------------------------------
// Pass 2: out = Oh / (r + 1e-15 * exp(M - m))   [exp folded: M - m - ln 1e15]
// Reads fp16 partials (f16x8, 16B/lane), writes fp32 Out (2x float4).
// ---------------------------------------------------------------------------
__global__ __launch_bounds__(256) void attn_epilogue(
    float* __restrict__ Out, const _Float16* __restrict__ Oh,
    const float* __restrict__ mrow, const float* __restrict__ rrow,
    const float* __restrict__ gmax)
{
    const int idx = blockIdx.x * 256 + threadIdx.x;  // 8-elem chunk index
    const int row = idx >> 4;                        // 16 chunks per 128-col row
    const float M = *gmax;
    float e = M - mrow[row] - 34.538776394910684f;   // + ln(1e-15)
    e = fminf(e, 85.f);                              // overflow guard
    const float inv = 1.0f / (rrow[row] + __expf(e));
    f16x8 h = *(const f16x8*)&Oh[(size_t)idx * 8];
    float4 o0, o1;
    o0.x = (float)h[0] * inv; o0.y = (float)h[1] * inv;
    o0.z = (float)h[2] * inv; o0.w = (float)h[3] * inv;
    o1.x = (float)h[4] * inv; o1.y = (float)h[5] * inv;
    o1.z = (float)h[6] * inv; o1.w = (float)h[7] * inv;
    ((float4*)Out)[idx * 2]     = o0;
    ((float4*)Out)[idx * 2 + 1] = o1;
}

extern "C" void kernel_launch(void* const* d_in, const int* in_sizes, int n_in,
                              void* d_out, int out_size, void* d_ws, size_t ws_size,
                              hipStream_t stream)
{
    const float* q = (const float*)d_in[0];
    const float* k = (const float*)d_in[1];
    const float* v = (const float*)d_in[2];
    // d_in[3] (attn_mask) is never read: causality is structural.
    float* out = (float*)d_out;
    // ws layout: Oh fp16 (16 MB) | mrow, rrow (2 x 256 KB) | gmax
    _Float16* oh   = (_Float16*)d_ws;
    float*    mrow = (float*)(oh + (size_t)NROW * DIM);
    float*    rrow = mrow + NROW;
    float*    gmax = rrow + NROW;

    hipMemsetAsync(gmax, 0, sizeof(float), stream);  // M init = 0 (mask zeros)

    attn_pass1<<<dim3(BHN * NQB), 512, 0, stream>>>(q, k, v, oh, mrow, rrow, gmax);

    const int n8 = NROW * DIM / 8;
    attn_epilogue<<<n8 / 256, 256, 0, stream>>>(out, oh, mrow, rrow, gmax);
}

// Round 20
// 91.315 us; speedup vs baseline: 1.0032x; 1.0032x over previous
//
#include <hip/hip_runtime.h>
#include <hip/hip_bf16.h>

#define BHN 64
#define LSEQ 1024
#define DIM 128
#define BM 128
#define BN 64
#define NQB (LSEQ / DIM)  // unused placeholder guard
#undef NQB
#define NQB (LSEQ / BM)   // 8 q-blocks per bh
#define NROW (BHN * LSEQ) // 65536 rows

typedef _Float16 f16x4 __attribute__((ext_vector_type(4)));
typedef _Float16 f16x8 __attribute__((ext_vector_type(8)));
typedef float f32x4 __attribute__((ext_vector_type(4)));

// Raw LDS-only barrier: orders DS ops (lgkmcnt) and syncs waves WITHOUT the
// __syncthreads() vmcnt(0) drain -- register-destined global prefetch loads
// stay in flight across it (m97 drain analysis; HK raw-barrier pattern).
__device__ __forceinline__ void lds_barrier() {
    asm volatile("" ::: "memory");                       // compiler fence
    asm volatile("s_waitcnt lgkmcnt(0)" ::: "memory");   // publish LDS writes
    __builtin_amdgcn_s_barrier();
    __builtin_amdgcn_sched_barrier(0);                   // no hoisting past (rule #18)
}

// ---------------------------------------------------------------------------
// Pass 1: R19 (= R12 plateau) with ONE change: __syncthreads() -> lds_barrier.
// The compiler's vmcnt(0) drain before s_barrier nullified the t+2 prefetch
// every tile (the profile shows 2.5% MfmaUtil / 5% VALUBusy: pure stall).
// With the raw barrier the prefetch spans a full iteration (~2-4k cyc >> 900
// cyc HBM latency). Everything else identical: BM=128, 512 thr, dbuf LDS
// 68608 B (2 blocks/CU, 16 waves/CU), fp16 swapped-QK^T flash tile,
// lane-local softmax, re-indexed zero-shuffle PV, fp16 workspace O.
// ---------------------------------------------------------------------------
__global__ __launch_bounds__(512, 4) void attn_pass1(
    const float* __restrict__ Q, const float* __restrict__ K,
    const float* __restrict__ V, _Float16* __restrict__ Oh,
    float* __restrict__ mrow, float* __restrict__ rrow, float* __restrict__ gmax)
{
    __shared__ _Float16 Kf[2][BN][132];   // 33792 B, QK reads conflict-free
    __shared__ _Float16 Vt[2][DIM][68];   // 34816 B; V transposed

    const int tid  = threadIdx.x;
    const int wave = tid >> 6;
    const int lane = tid & 63;
    const int g    = lane >> 4;   // 0..3 lane group
    const int ln   = lane & 15;
    const int L    = blockIdx.x;
    const int i6   = (L >> 6) & 7;
    const int qb   = (L < 256) ? (NQB - 1 - i6) : (i6 & 3);  // pair-sum = 7
    const int bh   = L & 63;                                  // same bh -> same XCD
    const int qrow0 = qb * BM + wave * 16;

    const float* qp = Q + (size_t)bh * LSEQ * DIM;
    const float* kp = K + (size_t)bh * LSEQ * DIM;
    const float* vp = V + (size_t)bh * LSEQ * DIM;

    // V staging role: 4x4 block per thread (rows 4*vrp.., cols vc..vc+3)
    const int vrp = tid >> 5;        // 0..15
    const int vc  = (tid & 31) * 4;  // 0..124

    // ---- pipeline registers (one tile in flight) ----
    float4 kreg[4];
    float4 vreg[4];   // vreg[i] = V[kv0 + 4*vrp + i][vc..vc+3]

    auto issue = [&](int kv0) {
        #pragma unroll
        for (int i = 0; i < 4; ++i) {
            const int f4  = i * 512 + tid;
            const int row = f4 >> 5;
            const int cc  = (f4 & 31) * 4;
            kreg[i] = *(const float4*)(kp + (size_t)(kv0 + row) * DIM + cc);
        }
        #pragma unroll
        for (int i = 0; i < 4; ++i)   // coalesced: half-wave = one 512B row seg
            vreg[i] = *(const float4*)(vp + (size_t)(kv0 + 4 * vrp + i) * DIM + vc);
    };

    auto convert_stage = [&](int b) {   // fp32 regs -> fp16 -> LDS buf b
        #pragma unroll
        for (int i = 0; i < 4; ++i) {
            const int f4  = i * 512 + tid;
            const int row = f4 >> 5;
            const int cc  = (f4 & 31) * 4;
            f16x4 h4;
            h4[0] = (_Float16)kreg[i].x; h4[1] = (_Float16)kreg[i].y;
            h4[2] = (_Float16)kreg[i].z; h4[3] = (_Float16)kreg[i].w;
            *(f16x4*)&Kf[b][row][cc] = h4;
        }
        // 4x4 in-register transpose -> column writes (ds_write_b64)
        const float* v0 = (const float*)&vreg[0];
        const float* v1 = (const float*)&vreg[1];
        const float* v2 = (const float*)&vreg[2];
        const float* v3 = (const float*)&vreg[3];
        #pragma unroll
        for (int jj = 0; jj < 4; ++jj) {
            f16x4 t;
            t[0] = (_Float16)v0[jj]; t[1] = (_Float16)v1[jj];
            t[2] = (_Float16)v2[jj]; t[3] = (_Float16)v3[jj];
            *(f16x4*)&Vt[b][vc + jj][4 * vrp] = t;
        }
    };

    // --- Q fragments (B-operand of swapped QK): lane holds
    //     Q[qrow0+ln][kc*32 + g*8 + e] in fp16 ---
    f16x8 qf[4];
    {
        const float* qrow = qp + (size_t)(qrow0 + ln) * DIM;
        #pragma unroll
        for (int kc = 0; kc < 4; ++kc) {
            const int d0 = kc * 32 + g * 8;
            float4 f0 = *(const float4*)(qrow + d0);
            float4 f1 = *(const float4*)(qrow + d0 + 4);
            f16x8 h;
            h[0] = (_Float16)f0.x; h[1] = (_Float16)f0.y;
            h[2] = (_Float16)f0.z; h[3] = (_Float16)f0.w;
            h[4] = (_Float16)f1.x; h[5] = (_Float16)f1.y;
            h[6] = (_Float16)f1.z; h[7] = (_Float16)f1.w;
            qf[kc] = h;
        }
    }

    float m_st = -1e30f, r_st = 0.f;   // per-lane scalars for q = qrow0+ln
    f32x4 o_acc[8];                    // row q_local=4g+r, col d=16ds+ln
    #pragma unroll
    for (int d = 0; d < 8; ++d) { f32x4 z = {0.f,0.f,0.f,0.f}; o_acc[d] = z; }

    const int nt = 2 * qb + 2;         // nt >= 2 always

    // --- prologue: tile 0 staged, tile 1 in flight ---
    issue(0);
    convert_stage(0);
    issue(BN);
    lds_barrier();

    int cur = 0;
    for (int t = 0; t < nt; ++t) {
        const int kv0 = t * BN;

        // stage t+1 into buf^1 FIRST (reads kreg/vreg of tile t+1), THEN
        // issue t+2 (loads now stay in flight across the raw barrier)
        if (t + 1 < nt) {
            convert_stage(cur ^ 1);
            if (t + 2 < nt) issue((t + 2) * BN);
        }

        if (qrow0 + 15 >= kv0) {   // wave-uniform: skip fully-masked tiles
            // --- S^T = K Q^T (single fp16 MFMA per 32-k chunk) ---
            f32x4 sacc[4];
            #pragma unroll
            for (int ns = 0; ns < 4; ++ns) { f32x4 z = {0.f,0.f,0.f,0.f}; sacc[ns] = z; }
            __builtin_amdgcn_s_setprio(1);
            #pragma unroll
            for (int ns = 0; ns < 4; ++ns) {
                const int n = ns * 16 + ln;   // A-fragment row
                #pragma unroll
                for (int kc = 0; kc < 4; ++kc) {
                    f16x8 kh_ = *(const f16x8*)&Kf[cur][n][kc * 32 + g * 8];
                    sacc[ns] = __builtin_amdgcn_mfma_f32_16x16x32_f16(kh_, qf[kc], sacc[ns], 0, 0, 0);
                }
            }
            __builtin_amdgcn_s_setprio(0);

            // --- causal mask where the tile crosses the diagonal ---
            if (kv0 + BN - 1 > qrow0) {
                const int qm = qrow0 + ln - kv0 - 4 * g;  // mask if 16ns+j > qm
                #pragma unroll
                for (int ns = 0; ns < 4; ++ns)
                    #pragma unroll
                    for (int j = 0; j < 4; ++j)
                        if (16 * ns + j > qm) sacc[ns][j] = -1e30f;
            }

            // --- online softmax: 16 lane-local values + 2 shfl_xor reduces ---
            float tm = -1e30f;
            #pragma unroll
            for (int ns = 0; ns < 4; ++ns)
                #pragma unroll
                for (int j = 0; j < 4; ++j) tm = fmaxf(tm, sacc[ns][j]);
            tm = fmaxf(tm, __shfl_xor(tm, 16));
            tm = fmaxf(tm, __shfl_xor(tm, 32));
            const float mn = fmaxf(m_st, tm);
            const float sc = __expf(m_st - mn);
            float pr[4][4];
            float ts = 0.f;
            #pragma unroll
            for (int ns = 0; ns < 4; ++ns)
                #pragma unroll
                for (int j = 0; j < 4; ++j) {
                    const float pv = __expf(sacc[ns][j] - mn);
                    pr[ns][j] = pv;
                    ts += pv;
                }
            ts += __shfl_xor(ts, 16);
            ts += __shfl_xor(ts, 32);
            r_st = r_st * sc + ts;
            m_st = mn;

            // rescale factors for accumulator rows (q_local=4g+r -> lane 4g+r)
            float scr[4];
            #pragma unroll
            for (int r = 0; r < 4; ++r) scr[r] = __shfl(sc, 4 * g + r);
            #pragma unroll
            for (int d = 0; d < 8; ++d) {
                o_acc[d][0] *= scr[0]; o_acc[d][1] *= scr[1];
                o_acc[d][2] *= scr[2]; o_acc[d][3] *= scr[3];
            }

            // --- PV, re-indexed contraction: A-frag is the lane's own P ---
            f16x8 pa0, pa1;
            #pragma unroll
            for (int j = 0; j < 4; ++j) {
                pa0[j]     = (_Float16)pr[0][j];
                pa0[4 + j] = (_Float16)pr[1][j];
                pa1[j]     = (_Float16)pr[2][j];
                pa1[4 + j] = (_Float16)pr[3][j];
            }
            __builtin_amdgcn_s_setprio(1);
            #pragma unroll
            for (int ds = 0; ds < 8; ++ds) {
                const int dc = ds * 16 + ln;
                f16x4 v0 = *(const f16x4*)&Vt[cur][dc][4 * g];
                f16x4 v1 = *(const f16x4*)&Vt[cur][dc][16 + 4 * g];
                f16x8 bv0;
                #pragma unroll
                for (int j = 0; j < 4; ++j) { bv0[j] = v0[j]; bv0[4 + j] = v1[j]; }
                o_acc[ds] = __builtin_amdgcn_mfma_f32_16x16x32_f16(pa0, bv0, o_acc[ds], 0, 0, 0);
                f16x4 v2 = *(const f16x4*)&Vt[cur][dc][32 + 4 * g];
                f16x4 v3 = *(const f16x4*)&Vt[cur][dc][48 + 4 * g];
                f16x8 bv1;
                #pragma unroll
                for (int j = 0; j < 4; ++j) { bv1[j] = v2[j]; bv1[4 + j] = v3[j]; }
                o_acc[ds] = __builtin_amdgcn_mfma_f32_16x16x32_f16(pa1, bv1, o_acc[ds], 0, 0, 0);
            }
            __builtin_amdgcn_s_setprio(0);
        }

        lds_barrier();   // publish stage(t+1); prefetch loads stay in flight
        cur ^= 1;
    }

    // --- write unnormalized O as fp16 to workspace (q = qrow0+4g+r, d = 16ds+ln) ---
    #pragma unroll
    for (int ds = 0; ds < 8; ++ds) {
        const int dc = ds * 16 + ln;
        #pragma unroll
        for (int r = 0; r < 4; ++r) {
            const int qr = qrow0 + g * 4 + r;
            Oh[((size_t)bh * LSEQ + qr) * DIM + dc] = (_Float16)o_acc[ds][r];
        }
    }
    if (lane < 16) {   // per-lane stats live at q = qrow0 + lane (g = 0)
        mrow[bh * LSEQ + qrow0 + lane] = m_st;
        rrow[bh * LSEQ + qrow0 + lane] = r_st;
    }
    float bm = m_st;
    #pragma unroll
    for (int off = 32; off >= 1; off >>= 1) bm = fmaxf(bm, __shfl_xor(bm, off));
    if (lane == 0) atomicMax((int*)gmax, __float_as_int(bm));
    // int-compare max valid: gmax init +0.0f; negatives always lose (the
    // reference's global max includes the mask's zeros).
}

// ---------------------------------------------------------------------------
// Pass 2: out = Oh / (r + 1e-15 * exp(M - m))   [exp folded: M - m - ln 1e15]
// Reads fp16 partials (f16x8, 16B/lane), writes fp32 Out (2x float4).
// ---------------------------------------------------------------------------
__global__ __launch_bounds__(256) void attn_epilogue(
    float* __restrict__ Out, const _Float16* __restrict__ Oh,
    const float* __restrict__ mrow, const float* __restrict__ rrow,
    const float* __restrict__ gmax)
{
    const int idx = blockIdx.x * 256 + threadIdx.x;  // 8-elem chunk index
    const int row = idx >> 4;                        // 16 chunks per 128-col row
    const float M = *gmax;
    float e = M - mrow[row] - 34.538776394910684f;   // + ln(1e-15)
    e = fminf(e, 85.f);                              // overflow guard
    const float inv = 1.0f / (rrow[row] + __expf(e));
    f16x8 h = *(const f16x8*)&Oh[(size_t)idx * 8];
    float4 o0, o1;
    o0.x = (float)h[0] * inv; o0.y = (float)h[1] * inv;
    o0.z = (float)h[2] * inv; o0.w = (float)h[3] * inv;
    o1.x = (float)h[4] * inv; o1.y = (float)h[5] * inv;
    o1.z = (float)h[6] * inv; o1.w = (float)h[7] * inv;
    ((float4*)Out)[idx * 2]     = o0;
    ((float4*)Out)[idx * 2 + 1] = o1;
}

extern "C" void kernel_launch(void* const* d_in, const int* in_sizes, int n_in,
                              void* d_out, int out_size, void* d_ws, size_t ws_size,
                              hipStream_t stream)
{
    const float* q = (const float*)d_in[0];
    const float* k = (const float*)d_in[1];
    const float* v = (const float*)d_in[2];
    // d_in[3] (attn_mask) is never read: causality is structural.
    float* out = (float*)d_out;
    // ws layout: Oh fp16 (16 MB) | mrow, rrow (2 x 256 KB) | gmax
    _Float16* oh   = (_Float16*)d_ws;
    float*    mrow = (float*)(oh + (size_t)NROW * DIM);
    float*    rrow = mrow + NROW;
    float*    gmax = rrow + NROW;

    hipMemsetAsync(gmax, 0, sizeof(float), stream);  // M init = 0 (mask zeros)

    attn_pass1<<<dim3(BHN * NQB), 512, 0, stream>>>(q, k, v, oh, mrow, rrow, gmax);

    const int n8 = NROW * DIM / 8;
    attn_epilogue<<<n8 / 256, 256, 0, stream>>>(out, oh, mrow, rrow, gmax);
}